// Round 6
// baseline (408.522 us; speedup 1.0000x reference)
//
#include <hip/hip_runtime.h>
#include <math.h>

#define BSZ 8192
#define DDIM 512
#define EMA_C 0.99
// acc is computed directly in logit scale: each side scaled by 8/||x|| so
// acc = 64*cos. 8 is an exact power of two -> scaling is lossless in fp16/fp32.
#define SC 64.0f
#define NFINAL 32
#define NT 24  // virtual-K tiles: 3 terms x 8 tiles (BK=64, K_real=512)

typedef _Float16 f16;
typedef _Float16 half8 __attribute__((ext_vector_type(8)));
typedef float f32x4 __attribute__((ext_vector_type(4)));

__device__ __forceinline__ void gload16(const void* g, void* l) {
    __builtin_amdgcn_global_load_lds(
        (const __attribute__((address_space(1))) void*)g,
        (__attribute__((address_space(3))) void*)l, 16, 0, 0);
}

#define BAR()   __builtin_amdgcn_s_barrier()
#define SBZ()   __builtin_amdgcn_sched_barrier(0)
#define LGKM0() asm volatile("s_waitcnt lgkmcnt(0)" ::: "memory")
#define WAITV(N) asm volatile("s_waitcnt vmcnt(" #N ")" ::: "memory")

// Normalize rows, scale by 8/||x||, split into fp16 hi + lo, store row-major.
// Also zeroes the stats region (pos/neg/Tsum/lossAcc/ticket) — ws is 0xAA-poisoned.
__global__ void prep_kernel(const float* __restrict__ f1,
                            const float* __restrict__ f2,
                            f16* __restrict__ Ah, f16* __restrict__ Al,
                            f16* __restrict__ Bh, f16* __restrict__ Bl,
                            float* __restrict__ stats) {
    if (blockIdx.y == 0 && blockIdx.x < 25) {
        int idx = blockIdx.x * 256 + threadIdx.x;
        if (idx < (3 * BSZ + 4) / 4)
            reinterpret_cast<float4*>(stats)[idx] = make_float4(0.f, 0.f, 0.f, 0.f);
    }
    const int w = threadIdx.x >> 6, l = threadIdx.x & 63;
    const int row = blockIdx.x * 4 + w;
    const float* src = (blockIdx.y == 0) ? f1 : f2;
    f16* dh = (blockIdx.y == 0) ? Ah : Bh;
    f16* dl = (blockIdx.y == 0) ? Al : Bl;
    const float4* p = reinterpret_cast<const float4*>(src + (size_t)row * DDIM);
    float4 v0 = p[l * 2], v1 = p[l * 2 + 1];
    float s = v0.x * v0.x + v0.y * v0.y + v0.z * v0.z + v0.w * v0.w +
              v1.x * v1.x + v1.y * v1.y + v1.z * v1.z + v1.w * v1.w;
#pragma unroll
    for (int off = 32; off; off >>= 1) s += __shfl_xor(s, off);
    const float g = 8.0f / sqrtf(s);
    float x[8] = {v0.x, v0.y, v0.z, v0.w, v1.x, v1.y, v1.z, v1.w};
    half8 h8, l8;
#pragma unroll
    for (int e = 0; e < 8; ++e) {
        float xs = x[e] * g;
        f16 hi = (f16)xs;
        h8[e] = hi;
        l8[e] = (f16)(xs - (float)hi);
    }
    *reinterpret_cast<half8*>(dh + (size_t)row * DDIM + l * 8) = h8;
    *reinterpret_cast<half8*>(dl + (size_t)row * DDIM + l * 8) = l8;
}

// ---------------------------------------------------------------------------
// 8-phase-style counted-vmcnt GEMM (T3+T4+T5), virtual K = 1536:
//   tiles 0-7: Ah*Bh, 8-15: Ah*Bl, 16-23: Al*Bh  (BK=64 real-k per tile)
// 256x256 block, 8 waves (2Mx4N), wave tile 128x64, MFMA 16x16x32 f16.
// LDS: 2 bufs x (A[256][64] + B[256][64]) f16 = 128 KiB. Rows are 128B,
// slot-swizzled: 16B-slot s of row r holds k-group s ^ (r&7)  [both-sides swz].
// Loop: WAITV(8) (counted — next tile's 8 loads stay in flight) ; raw BAR ;
// 4 phases {8 ds_read ; BAR ; lgkmcnt(0)+sched_barrier ; prio1 ; 16 MFMA ;
// prio0 ; BAR} ; stage tile t+2 into the just-freed buffer.
// ---------------------------------------------------------------------------
__launch_bounds__(512, 2)
__global__ void gemm_pass_kernel(const f16* __restrict__ Ah, const f16* __restrict__ Al,
                                 const f16* __restrict__ Bh, const f16* __restrict__ Bl,
                                 const int* __restrict__ label,
                                 float* __restrict__ pos,
                                 float* __restrict__ negv,
                                 float* __restrict__ Tsum) {
    __shared__ __align__(16) char LDS[131072];

    const int tid = threadIdx.x, w = tid >> 6, l = tid & 63;
    const int rowBase = blockIdx.y * 256;
    const int colBase = blockIdx.x * 256;

    // ---- staging addressing ----
    // lane writes LDS bytes (region + q*8192 + w*1024 + l*16): row q*64+w*8+(l>>3),
    // slot l&7. Source pre-swizzled: k-group kg = (l&7) ^ (l>>3) = slot ^ (row&7).
    const int kg = (l & 7) ^ (l >> 3);
    const int wq = w * 1024;  // wave-uniform LDS dest component
    const size_t aOff0 = (size_t)(rowBase + 0 * 64 + w * 8 + (l >> 3)) * DDIM + kg * 8;
    const size_t aOff1 = (size_t)(rowBase + 1 * 64 + w * 8 + (l >> 3)) * DDIM + kg * 8;
    const size_t aOff2 = (size_t)(rowBase + 2 * 64 + w * 8 + (l >> 3)) * DDIM + kg * 8;
    const size_t aOff3 = (size_t)(rowBase + 3 * 64 + w * 8 + (l >> 3)) * DDIM + kg * 8;
    const size_t bOff0 = (size_t)(colBase + 0 * 64 + w * 8 + (l >> 3)) * DDIM + kg * 8;
    const size_t bOff1 = (size_t)(colBase + 1 * 64 + w * 8 + (l >> 3)) * DDIM + kg * 8;
    const size_t bOff2 = (size_t)(colBase + 2 * 64 + w * 8 + (l >> 3)) * DDIM + kg * 8;
    const size_t bOff3 = (size_t)(colBase + 3 * 64 + w * 8 + (l >> 3)) * DDIM + kg * 8;

#define STAGE(sA, sB, kE, bo) do {                                   \
    gload16((sA) + aOff0 + (kE), &LDS[(bo) + 0 * 8192 + wq]);        \
    gload16((sA) + aOff1 + (kE), &LDS[(bo) + 1 * 8192 + wq]);        \
    gload16((sA) + aOff2 + (kE), &LDS[(bo) + 2 * 8192 + wq]);        \
    gload16((sA) + aOff3 + (kE), &LDS[(bo) + 3 * 8192 + wq]);        \
    gload16((sB) + bOff0 + (kE), &LDS[(bo) + 32768 + 0 * 8192 + wq]);\
    gload16((sB) + bOff1 + (kE), &LDS[(bo) + 32768 + 1 * 8192 + wq]);\
    gload16((sB) + bOff2 + (kE), &LDS[(bo) + 32768 + 2 * 8192 + wq]);\
    gload16((sB) + bOff3 + (kE), &LDS[(bo) + 32768 + 3 * 8192 + wq]);\
  } while (0)

    // ---- fragment read addressing (swizzled reads) ----
    const int wrow = w >> 2, wcol = w & 3;  // 2 x 4 wave grid
    const int arl = l & 15;
    const int aRow = (wrow * 128 + arl) * 128;       // byte base within A region
    const int bRow = (wcol * 64 + arl) * 128;        // byte base within B region
    // slot index = ks*4 + (l>>4); swizzled by row&7 == arl&7
    const int sb0 = (((l >> 4) + 0) ^ (arl & 7)) * 16;
    const int sb1 = (((l >> 4) + 4) ^ (arl & 7)) * 16;

#define LD8(off) (*reinterpret_cast<const half8*>(&LDS[(off)]))
#define PHASE_READ_A(bo, H, SBX) do {                          \
    aF[0] = LD8((bo) + aRow + ((H) * 4 + 0) * 2048 + (SBX));   \
    aF[1] = LD8((bo) + aRow + ((H) * 4 + 1) * 2048 + (SBX));   \
    aF[2] = LD8((bo) + aRow + ((H) * 4 + 2) * 2048 + (SBX));   \
    aF[3] = LD8((bo) + aRow + ((H) * 4 + 3) * 2048 + (SBX));   \
  } while (0)
#define PHASE_READ_B(bo, BF, SBX) do {                         \
    BF[0] = LD8((bo) + 32768 + bRow + 0 * 2048 + (SBX));       \
    BF[1] = LD8((bo) + 32768 + bRow + 1 * 2048 + (SBX));       \
    BF[2] = LD8((bo) + 32768 + bRow + 2 * 2048 + (SBX));       \
    BF[3] = LD8((bo) + 32768 + bRow + 3 * 2048 + (SBX));       \
  } while (0)
#define PHASE_MFMA(H, BF) do {                                 \
    __builtin_amdgcn_s_setprio(1);                             \
    _Pragma("unroll")                                          \
    for (int rt = 0; rt < 4; ++rt) {                           \
      _Pragma("unroll")                                        \
      for (int ct = 0; ct < 4; ++ct)                           \
        acc[(H) * 4 + rt][ct] = __builtin_amdgcn_mfma_f32_16x16x32_f16( \
            aF[rt], BF[ct], acc[(H) * 4 + rt][ct], 0, 0, 0);   \
    }                                                          \
    __builtin_amdgcn_s_setprio(0);                             \
  } while (0)
#define TILE_BODY(bo) do {                                     \
    half8 aF[4], bK0[4], bK1[4];                               \
    PHASE_READ_A(bo, 0, sb0); PHASE_READ_B(bo, bK0, sb0);      \
    BAR(); LGKM0(); SBZ(); PHASE_MFMA(0, bK0); BAR();          \
    PHASE_READ_A(bo, 0, sb1); PHASE_READ_B(bo, bK1, sb1);      \
    BAR(); LGKM0(); SBZ(); PHASE_MFMA(0, bK1); BAR();          \
    PHASE_READ_A(bo, 1, sb0);                                  \
    BAR(); LGKM0(); SBZ(); PHASE_MFMA(1, bK0); BAR();          \
    PHASE_READ_A(bo, 1, sb1);                                  \
    BAR(); LGKM0(); SBZ(); PHASE_MFMA(1, bK1); BAR();          \
  } while (0)

    f32x4 acc[8][4];
#pragma unroll
    for (int rt = 0; rt < 8; ++rt)
#pragma unroll
        for (int ct = 0; ct < 4; ++ct) acc[rt][ct] = (f32x4){0.f, 0.f, 0.f, 0.f};

    // prologue: stage tiles 0 and 1 (both are Ah/Bh, real-k 0 and 64)
    STAGE(Ah, Bh, 0, 0);
    STAGE(Ah, Bh, 64, 65536);

#pragma unroll 1
    for (int t = 0; t < NT - 1; ++t) {
        const int bo = (t & 1) << 16;
        WAITV(8);  // drain own 8 oldest (this tile); next tile's 8 stay in flight
        BAR();
        TILE_BODY(bo);
        const int tt = t + 2;
        if (tt < NT) {  // stage tile t+2 into the buffer just freed by TILE_BODY
            const f16* sA = (tt < 16) ? Ah : Al;
            const f16* sB = (tt < 8) ? Bh : ((tt < 16) ? Bl : Bh);
            const size_t kE = (size_t)(tt & 7) * 64;
            SBZ();  // keep gloads from scheduling before the last-reader barrier
            STAGE(sA, sB, kE, bo);
        }
    }
    // peeled tail: nothing younger in flight -> must drain fully
    WAITV(0);
    BAR();
    TILE_BODY(((NT - 1) & 1) << 16);

    // ---- epilogue: clip, mask, exp, per-row sum/max ----
    // C/D: col = lane&15, row = (lane>>4)*4 + reg  [m89-verified layout]
    const int rowB2 = rowBase + wrow * 128;
    const int colB2 = colBase + wcol * 64;
    const int cl = l & 15, h = l >> 4;

    int lcs[4];
#pragma unroll
    for (int ct = 0; ct < 4; ++ct) lcs[ct] = label[colB2 + ct * 16 + cl];

    float psum[8][4], pmax[8][4];
#pragma unroll
    for (int rt = 0; rt < 8; ++rt)
#pragma unroll
        for (int reg = 0; reg < 4; ++reg) { psum[rt][reg] = 0.f; pmax[rt][reg] = 0.f; }

#pragma unroll
    for (int rt = 0; rt < 8; ++rt) {
        int lr[4];
#pragma unroll
        for (int reg = 0; reg < 4; ++reg) lr[reg] = label[rowB2 + rt * 16 + h * 4 + reg];
#pragma unroll
        for (int ct = 0; ct < 4; ++ct) {
            const int gcol = colB2 + ct * 16 + cl;
#pragma unroll
            for (int reg = 0; reg < 4; ++reg) {
                float v = acc[rt][ct][reg];
                v = fminf(fmaxf(v, -SC), SC);  // clip in logit units (+-64)
                const int grow = rowB2 + rt * 16 + h * 4 + reg;
                if (grow == gcol) {
                    pos[grow] = v;  // scaled diag; exactly one writer chip-wide
                } else {
                    if (lr[reg] == lcs[ct]) v = 0.0f;  // same-label mask
                    psum[rt][reg] += __expf(v);        // e^(64*cos)
                    pmax[rt][reg] = fmaxf(pmax[rt][reg], v);
                }
            }
        }
    }

#pragma unroll
    for (int rt = 0; rt < 8; ++rt)
#pragma unroll
        for (int reg = 0; reg < 4; ++reg) {
            float s = psum[rt][reg], mx = pmax[rt][reg];
#pragma unroll
            for (int m = 1; m <= 8; m <<= 1) {
                s += __shfl_xor(s, m);
                mx = fmaxf(mx, __shfl_xor(mx, m));
            }
            if (cl == 0) {
                const int grow = rowB2 + rt * 16 + h * 4 + reg;
                atomicAdd(&Tsum[grow], s);
                // values >= 0 -> int compare == float compare; init bits 0.0f
                atomicMax(reinterpret_cast<int*>(&negv[grow]), __float_as_int(mx));
            }
        }
}

// 32 blocks x 256 threads: each thread owns exactly one row. Every block
// redundantly computes the (bit-identical) m-sum; per-row loss in double;
// block partial -> f64 atomicAdd; last block (ticket) writes out.
__global__ void final_kernel(const float* __restrict__ pos,
                             const float* __restrict__ negv,
                             const float* __restrict__ Tsum,
                             double* __restrict__ lossAcc,
                             int* __restrict__ ticket,
                             float* __restrict__ out) {
    __shared__ double sd[256];
    const int t = threadIdx.x;

    // ---- mLogit = SC*m = EMA * sum(pos-neg)/B ----
    double s = 0.0;
    for (int i = t; i < BSZ; i += 256) s += (double)pos[i] - (double)negv[i];
    sd[t] = s;
    __syncthreads();
    for (int off = 128; off; off >>= 1) {
        if (t < off) sd[t] += sd[t + off];
        __syncthreads();
    }
    const double mLogit = EMA_C * sd[0] / BSZ;
    __syncthreads();

    // ---- one row per thread: loss = log(T + exp(d)) - d, stable ----
    const int row = blockIdx.x * 256 + t;  // NFINAL*256 == BSZ
    double d  = (double)pos[row] - mLogit;
    double lt = log((double)Tsum[row]);
    double l;
    if (d >= lt) l = log1p(exp(lt - d));
    else         l = (lt - d) + log1p(exp(d - lt));
    sd[t] = l;
    __syncthreads();
    for (int off = 128; off; off >>= 1) {
        if (t < off) sd[t] += sd[t + off];
        __syncthreads();
    }
    if (t == 0) {
        atomicAdd(lossAcc, sd[0]);
        __threadfence();
        int done = atomicAdd(ticket, 1);
        if (done == NFINAL - 1) {
            double total = atomicAdd(lossAcc, 0.0);  // RMW read: coherent total
            out[0] = (float)(total / BSZ);
        }
    }
}

extern "C" void kernel_launch(void* const* d_in, const int* in_sizes, int n_in,
                              void* d_out, int out_size, void* d_ws, size_t ws_size,
                              hipStream_t stream) {
    const float* f1    = (const float*)d_in[0];
    const float* f2    = (const float*)d_in[1];
    const int*   label = (const int*)d_in[2];
    float* out = (float*)d_out;

    // ws layout: pos[B], neg[B], Tsum[B] (f32), lossAcc (f64), ticket (i32),
    // pad to 16B, then Ah/Al/Bh/Bl fp16 matrices.
    float* stats = (float*)d_ws;
    float* pos   = stats;
    float* neg   = stats + BSZ;
    float* Tsum  = stats + 2 * BSZ;
    double* lossAcc = (double*)(stats + 3 * BSZ);       // byte 98304, 8-aligned
    int* ticket  = (int*)(stats + 3 * BSZ + 2);
    f16* Ah = (f16*)((char*)d_ws + 3 * BSZ * sizeof(float) + 16);
    f16* Al = Ah + (size_t)BSZ * DDIM;
    f16* Bh = Al + (size_t)BSZ * DDIM;
    f16* Bl = Bh + (size_t)BSZ * DDIM;

    prep_kernel<<<dim3(BSZ / 4, 2), dim3(256), 0, stream>>>(f1, f2, Ah, Al, Bh, Bl, stats);

    gemm_pass_kernel<<<dim3(BSZ / 256, BSZ / 256), dim3(512), 0, stream>>>(
        Ah, Al, Bh, Bl, label, pos, neg, Tsum);

    final_kernel<<<dim3(NFINAL), dim3(256), 0, stream>>>(pos, neg, Tsum, lossAcc, ticket, out);
}